// Round 1
// baseline (2354.763 us; speedup 1.0000x reference)
//
#include <hip/hip_runtime.h>
#include <hip/hip_bf16.h>

// Cost-volume: out[b,d,h,w] = sum_c |L[b,c,h,w] - R[b,c,h,4w-d]| (R=0 if 4w-d<0)
// B=8 C=32 H=256 W=512 WR=2048 D=48, f32.
//
// One workgroup per (b,h,w-tile of 256). LDS-stage L tile + R window,
// channel-chunked (8 ch/chunk). Each thread computes a 4w x 12d output block
// (48 accumulators) -> per channel: 1 L float4 + 7 R float4 LDS reads.
// R LDS rows XOR-swizzled at 16B-granule level (g ^= (g>>3)&7, involution)
// to kill the 16-float lane-stride bank aliasing.

#define BB 8
#define CC_TOT 32
#define HH 256
#define WW 512
#define WWR 2048
#define DD 48
#define WT 256        // w-tile
#define CCH 8         // channels per chunk
#define NCH (CC_TOT / CCH)
#define RWF 1088      // floats per staged R row (272 granules; 268 carry data)
#define RG 272        // 16B granules per R row
#define RG_USED 268

__global__ __launch_bounds__(256, 3)
void cost_volume_kernel(const float* __restrict__ Lp,
                        const float* __restrict__ Rp,
                        float* __restrict__ out) {
    __shared__ float Ls[CCH][WT];
    __shared__ float Rs[CCH][RWF];

    const int t = threadIdx.x;
    const int wg = blockIdx.x;          // 0..4095
    const int tile = wg & 1;            // 2 tiles per plane
    const int plane = wg >> 1;          // b*H + h
    const int h = plane & (HH - 1);
    const int b = plane >> 8;
    const int w0 = tile * WT;
    const int rbase = 4 * w0 - 48;      // global R col of staged float 0 (mult of 4)

    const int wb = t & 63;              // w-block: 4 consecutive w's
    const int db = t >> 6;              // d-block: 12 consecutive d's

    float acc[12][4];
#pragma unroll
    for (int j = 0; j < 12; ++j)
#pragma unroll
        for (int k = 0; k < 4; ++k) acc[j][k] = 0.f;

    // Per-thread R read granules: ga0..ga0+6 (original index space), swizzled.
    const int ga0 = 4 * wb - 3 * db + 9;
    int roff[7];
#pragma unroll
    for (int m = 0; m < 7; ++m) {
        int g = ga0 + m;
        roff[m] = g ^ ((g >> 3) & 7);   // swizzled granule
    }

    const size_t lrow = (size_t)(b * CC_TOT) * HH + h;         // row index base
    const float* Lbase = Lp + lrow * WW + w0;                  // + c*H*W
    const float* Rbase = Rp + lrow * WWR;                      // + c*H*WR

    for (int ch = 0; ch < NCH; ++ch) {
        __syncthreads();   // previous chunk's compute done before overwrite
        // ---- stage L: CCH*WT/4 = 512 float4, 2 per thread, coalesced ----
#pragma unroll
        for (int r = 0; r < 2; ++r) {
            int idx = t + 256 * r;          // 0..511
            int cc = idx >> 6;
            int i = idx & 63;
            float4 v = *(const float4*)(Lbase + (size_t)(ch * CCH + cc) * (HH * WW) + 4 * i);
            *(float4*)&Ls[cc][4 * i] = v;
        }
        // ---- stage R: CCH*RG = 2176 granules, swizzled write ----
#pragma unroll
        for (int r = 0; r < 9; ++r) {
            int idx = t + 256 * r;
            if (idx < CCH * RG) {
                int cc = idx / RG;
                int g = idx - cc * RG;
                float4 v = make_float4(0.f, 0.f, 0.f, 0.f);
                int col4 = rbase + 4 * g;
                if (g < RG_USED && col4 >= 0)
                    v = *(const float4*)(Rbase + (size_t)(ch * CCH + cc) * (HH * WWR) + col4);
                int gs = g ^ ((g >> 3) & 7);
                *(float4*)&Rs[cc][4 * gs] = v;
            }
        }
        __syncthreads();
        // ---- compute ----
#pragma unroll
        for (int cc = 0; cc < CCH; ++cc) {
            float4 lv = *(const float4*)&Ls[cc][4 * wb];
            float lvv[4] = {lv.x, lv.y, lv.z, lv.w};
            float rr[28];
#pragma unroll
            for (int m = 0; m < 7; ++m) {
                float4 rv = *(const float4*)&Rs[cc][4 * roff[m]];
                rr[4 * m + 0] = rv.x; rr[4 * m + 1] = rv.y;
                rr[4 * m + 2] = rv.z; rr[4 * m + 3] = rv.w;
            }
            // out(w=w0+4wb+k, d=12db+j) needs R float index rel = 12+4k-j
            // (relative to granule ga0), all compile-time.
#pragma unroll
            for (int j = 0; j < 12; ++j)
#pragma unroll
                for (int k = 0; k < 4; ++k)
                    acc[j][k] += fabsf(lvv[k] - rr[12 + 4 * k - j]);
        }
    }

    // ---- write out[b][d][h][w], coalesced float4 per lane ----
#pragma unroll
    for (int j = 0; j < 12; ++j) {
        int d = db * 12 + j;
        float4 v = make_float4(acc[j][0], acc[j][1], acc[j][2], acc[j][3]);
        *(float4*)(out + (((size_t)(b * DD + d) * HH + h) * WW) + w0 + 4 * wb) = v;
    }
}

extern "C" void kernel_launch(void* const* d_in, const int* in_sizes, int n_in,
                              void* d_out, int out_size, void* d_ws, size_t ws_size,
                              hipStream_t stream) {
    const float* L = (const float*)d_in[0];
    const float* R = (const float*)d_in[1];
    float* out = (float*)d_out;
    dim3 grid(BB * HH * (WW / WT));   // 4096
    dim3 block(256);
    hipLaunchKernelGGL(cost_volume_kernel, grid, block, 0, stream, L, R, out);
}